// Round 5
// baseline (300.275 us; speedup 1.0000x reference)
//
#include <hip/hip_runtime.h>
#include <stdint.h>

#define SLOPE 0.2f
#define HASH_SIZE 131072  // 2^17, load factor ~0.38 at C=50000
#define CHUNK 768         // online-softmax chunk (LDS-resident e values)

__device__ __forceinline__ float leakyf(float x) { return x >= 0.f ? x : SLOPE * x; }
__device__ __forceinline__ float sigmoidf(float x) { return 1.f / (1.f + expf(-x)); }
__device__ __forceinline__ unsigned short f2bf(float f) {
  union { float f; unsigned int i; } c; c.f = f;
  unsigned int u = c.i;
  return (unsigned short)((u + 0x7fffu + ((u >> 16) & 1u)) >> 16);  // RNE
}
__device__ __forceinline__ float bf2f(unsigned short u) {
  union { unsigned int i; float f; } c; c.i = ((unsigned int)u) << 16; return c.f;
}
// unpack 4 consecutive bf16 (8B) -> float4
__device__ __forceinline__ float4 ldbf4(const unsigned short* p) {
  uint2 v = *(const uint2*)p;
  union { unsigned int i; float f; } a, b, c, d;
  a.i = v.x << 16; b.i = v.x & 0xffff0000u;
  c.i = v.y << 16; d.i = v.y & 0xffff0000u;
  return make_float4(a.f, b.f, c.f, d.f);
}

// ---------- init scratch (deg/cursor zero, hash empty) ----------
__global__ void init_kernel(int* __restrict__ deg, int* __restrict__ cursor,
                            int* __restrict__ hkeys, float* __restrict__ hval,
                            int n, int H)
{
  int i = blockIdx.x * blockDim.x + threadIdx.x;
  int stride = gridDim.x * blockDim.x;
  for (int j = i; j < n; j += stride) { deg[j] = 0; cursor[j] = 0; }
  for (int j = i; j < H; j += stride) { hkeys[j] = -1; hval[j] = 0.f; }
}

// ---------- constraint hash build ----------
__global__ void hash_build(const int* __restrict__ cidx, const float* __restrict__ cval,
                           const int* __restrict__ ctype, const float* __restrict__ lc,
                           int* __restrict__ hkeys, float* __restrict__ hval,
                           int C, int n, int H)
{
  int i = blockIdx.x * blockDim.x + threadIdx.x;
  if (i >= C) return;
  int key = cidx[i] * n + cidx[C + i];
  float l = sigmoidf(lc[ctype[i]]) * 0.9f + 0.1f;   // lc = sig*(1-0.1)+0.1
  float w = l * cval[i];
  unsigned int slot = ((unsigned int)key * 2654435761u) & (unsigned int)(H - 1);
  while (true) {
    int prev = atomicCAS(&hkeys[slot], -1, key);
    if (prev == -1 || prev == key) break;
    slot = (slot + 1) & (unsigned int)(H - 1);
  }
  atomicAdd(&hval[slot], w);
}

// ---------- per-relation precompute: P3b[r][j] = rel[r]·att_w1[j,256:384] + att_b1[j] ----------
__global__ __launch_bounds__(128) void p3b_kernel(const float* __restrict__ rel,
                                                  const float* __restrict__ aw1,
                                                  const float* __restrict__ ab1,
                                                  float* __restrict__ P3b)
{
  int r = blockIdx.x; int j = threadIdx.x;
  __shared__ float rl[128];
  rl[j] = rel[r * 128 + j];
  __syncthreads();
  float acc = ab1[j];
  const float* wrow = aw1 + j * 384 + 256;
  #pragma unroll 4
  for (int k = 0; k < 128; ++k) acc += rl[k] * wrow[k];
  P3b[r * 128 + j] = acc;
}

// ---------- shared GEMM body (64x64 tile, 4x4 microtile, K=128) ----------
__device__ __forceinline__ void gemm_body(
    const float* __restrict__ A, const float* __restrict__ B,
    int ldb, int boff, int M, int m0, int n0,
    float (&acc)[4][4], float (*As)[68], float (*Bs)[68])
{
  const int tid = threadIdx.x;
  const int tx = tid & 15, ty = tid >> 4;
  const int lin = tid * 4;
  const int lm = lin >> 4;        // 0..63
  const int lk = lin & 15;        // 0,4,8,12

  for (int kk = 0; kk < 128; kk += 16) {
    __syncthreads();
    {
      int row = m0 + lm;
      if (row < M) {
        float4 v = *(const float4*)(A + row * 128 + kk + lk);
        As[lk + 0][lm] = v.x; As[lk + 1][lm] = v.y;
        As[lk + 2][lm] = v.z; As[lk + 3][lm] = v.w;
      } else {
        As[lk + 0][lm] = 0.f; As[lk + 1][lm] = 0.f;
        As[lk + 2][lm] = 0.f; As[lk + 3][lm] = 0.f;
      }
      int j = n0 + lm;  // N=128 exact, no guard needed
      float4 w = *(const float4*)(B + j * ldb + boff + kk + lk);
      Bs[lk + 0][lm] = w.x; Bs[lk + 1][lm] = w.y;
      Bs[lk + 2][lm] = w.z; Bs[lk + 3][lm] = w.w;
    }
    __syncthreads();
    #pragma unroll
    for (int k = 0; k < 16; ++k) {
      float a[4], b[4];
      #pragma unroll
      for (int i = 0; i < 4; ++i) a[i] = As[k][ty * 4 + i];
      #pragma unroll
      for (int j = 0; j < 4; ++j) b[j] = Bs[k][tx * 4 + j];
      #pragma unroll
      for (int i = 0; i < 4; ++i)
        #pragma unroll
        for (int j = 0; j < 4; ++j)
          acc[i][j] += a[i] * b[j];
    }
  }
}

// ---------- GEMM: C = A @ B^T (fp32 store + optional bf16 copy, or fused final epilogue) ----------
__global__ __launch_bounds__(256) void gemm_abt(
    const float* __restrict__ A,
    const float* __restrict__ B, int ldb, int boff, int M,
    float* __restrict__ Cb, unsigned short* __restrict__ C16, int epi,
    const float* __restrict__ Whb,
    const float* __restrict__ side,
    float* __restrict__ outp)
{
  __shared__ float As[16][68];
  __shared__ float Bs[16][68];
  const int m0 = blockIdx.x * 64;
  const int n0 = blockIdx.y * 64;
  float acc[4][4] = {};
  gemm_body(A, B, ldb, boff, M, m0, n0, acc, As, Bs);

  const int tx = (int)threadIdx.x & 15, ty = (int)threadIdx.x >> 4;
  #pragma unroll
  for (int i = 0; i < 4; ++i) {
    int row = m0 + ty * 4 + i;
    if (row >= M) continue;
    int idx0 = row * 128 + n0 + tx * 4;
    if (epi == 0) {
      float4 v4 = make_float4(acc[i][0], acc[i][1], acc[i][2], acc[i][3]);
      *(float4*)(Cb + idx0) = v4;
      if (C16) {
        ushort4 u; u.x = f2bf(v4.x); u.y = f2bf(v4.y); u.z = f2bf(v4.z); u.w = f2bf(v4.w);
        *(ushort4*)(C16 + idx0) = u;
      }
    } else {
      #pragma unroll
      for (int j = 0; j < 4; ++j) {
        int idx = idx0 + j;
        float w = Whb[idx];
        float s = side[idx];
        float hn = leakyf(w + s) + leakyf(acc[i][j]) + w;
        outp[idx] = hn > 0.f ? hn : (expf(hn) - 1.f);
      }
    }
  }
}

// ---------- fused 4-matrix GEMM -> bf16 outputs: P1/P2 = Wh@A1/A2^T, Q1/Q2 = Wh@G1/G2^T ----------
__global__ __launch_bounds__(256) void gemm4(
    const float* __restrict__ A,
    const float* __restrict__ aw1, const float* __restrict__ gw1,
    unsigned short* __restrict__ P1, unsigned short* __restrict__ P2,
    unsigned short* __restrict__ Q1, unsigned short* __restrict__ Q2, int M)
{
  __shared__ float As[16][68];
  __shared__ float Bs[16][68];
  const int mat = blockIdx.y >> 1;
  const int n0 = (blockIdx.y & 1) * 64;
  const int m0 = blockIdx.x * 64;
  const float* B; int ldb, boff; unsigned short* out;
  switch (mat) {
    case 0:  B = aw1; ldb = 384; boff = 0;   out = P1; break;
    case 1:  B = aw1; ldb = 384; boff = 128; out = P2; break;
    case 2:  B = gw1; ldb = 256; boff = 0;   out = Q1; break;
    default: B = gw1; ldb = 256; boff = 128; out = Q2; break;
  }
  float acc[4][4] = {};
  gemm_body(A, B, ldb, boff, M, m0, n0, acc, As, Bs);

  const int tx = (int)threadIdx.x & 15, ty = (int)threadIdx.x >> 4;
  #pragma unroll
  for (int i = 0; i < 4; ++i) {
    int row = m0 + ty * 4 + i;
    if (row >= M) continue;
    ushort4 u;
    u.x = f2bf(acc[i][0]); u.y = f2bf(acc[i][1]);
    u.z = f2bf(acc[i][2]); u.w = f2bf(acc[i][3]);
    *(ushort4*)(out + row * 128 + n0 + tx * 4) = u;
  }
}

// ---------- degree count ----------
__global__ void deg_kernel(const int* __restrict__ ei, int* __restrict__ deg, int E)
{
  int i = blockIdx.x * blockDim.x + threadIdx.x;
  if (i < E) atomicAdd(&deg[ei[i]], 1);
}

// ---------- exclusive scan of deg -> offs (single block, shfl-based) ----------
__global__ __launch_bounds__(1024) void scan_kernel(const int* __restrict__ deg,
                                                    int* __restrict__ offs, int n)
{
  const int ITEMS = (n + 1023) >> 10;    // <=16
  const int t = threadIdx.x;
  const int base = t * ITEMS;
  int local[16];
  int sum = 0;
  for (int i = 0; i < ITEMS; ++i) {
    int idx = base + i;
    int v = (idx < n) ? deg[idx] : 0;
    local[i] = sum;           // exclusive prefix within chunk
    sum += v;
  }
  __shared__ int wsum[16];
  int lane = t & 63, w = t >> 6;
  int x = sum;
  #pragma unroll
  for (int d = 1; d < 64; d <<= 1) {
    int y = __shfl_up(x, d, 64);
    if (lane >= d) x += y;
  }
  if (lane == 63) wsum[w] = x;
  __syncthreads();
  if (t == 0) {
    int acc2 = 0;
    for (int i = 0; i < 16; ++i) { int v = wsum[i]; wsum[i] = acc2; acc2 += v; }
  }
  __syncthreads();
  int texcl = wsum[w] + (x - sum);
  for (int i = 0; i < ITEMS; ++i) {
    int idx = base + i;
    if (idx < n) offs[idx] = texcl + local[i];
  }
}

// ---------- bucket edges by src: trs[pos] = (tgt, rtype), pos in CSR order ----------
__global__ void place_kernel(const int* __restrict__ ei, const int* __restrict__ etype,
                             const int* __restrict__ offs, int* __restrict__ cursor,
                             int2* __restrict__ trs, int E)
{
  int i = blockIdx.x * blockDim.x + threadIdx.x;
  if (i >= E) return;
  int s = ei[i];
  int pos = offs[s] + atomicAdd(&cursor[s], 1);
  trs[pos] = make_int2(ei[E + i], etype[i]);
}

// ---------- fused per-node: edge scores + online softmax + aggregation ----------
// One block (256 thr = 8 groups of 32 lanes) per node. src-side tables in registers.
__global__ __launch_bounds__(256) void fused_edge_node(
  const int* __restrict__ offs, const int* __restrict__ deg,
  const int2* __restrict__ trs,
  const unsigned short* __restrict__ P1, const unsigned short* __restrict__ P2,
  const float* __restrict__ P3b,
  const unsigned short* __restrict__ Q1, const unsigned short* __restrict__ Q2,
  const float* __restrict__ aw2,
  const float* __restrict__ gb1, const float* __restrict__ gw2,
  const float* __restrict__ gb2, const float* __restrict__ lgp,
  const int* __restrict__ hkeys, const float* __restrict__ hval,
  const unsigned short* __restrict__ Whb16, const float* __restrict__ Whb,
  float* __restrict__ side, float* __restrict__ Xb, int n, int H)
{
  const int node = blockIdx.x;
  const int tid = threadIdx.x;
  const int start = offs[node];
  const int cnt = deg[node];
  const int g = tid >> 5, l = tid & 31;
  const int t = tid & 127, jh = tid >> 7;   // aggregation: dim t, j-half jh

  __shared__ float sh_e[CHUNK];
  __shared__ float r4[4];
  __shared__ float red[256];
  __shared__ float sh_m, sh_alpha, sh_ssum;

  // per-group register preloads (src-side: one load per block, not per edge)
  float4 p1 = ldbf4(P1 + node * 128 + 4 * l);
  float4 q1 = ldbf4(Q1 + node * 128 + 4 * l);
  float4 w2 = *(const float4*)(aw2 + 4 * l);
  float4 b1 = *(const float4*)(gb1 + 4 * l);
  float4 g2 = *(const float4*)(gw2 + 4 * l);
  float gb2s = gb2[0];
  float lg = sigmoidf(lgp[0]) * 0.9f + 0.1f;

  if (tid == 0) { sh_m = -INFINITY; sh_ssum = 0.f; }
  float acc = 0.f;

  for (int base = 0; base < cnt; base += CHUNK) {
    int jmax = min(CHUNK, cnt - base);
    __syncthreads();   // sh_e reuse guard + sh_m/sh_ssum init visibility

    // ---- Phase A: per-edge scores into LDS (group-parallel) ----
    for (int j = g; j < jmax; j += 8) {
      int2 tr = trs[start + base + j];
      int tgt = tr.x, rt = tr.y;
      float4 p2 = ldbf4(P2 + tgt * 128 + 4 * l);
      float4 p3 = *(const float4*)(P3b + rt * 128 + 4 * l);
      float part = leakyf(p1.x + p2.x + p3.x) * w2.x
                 + leakyf(p1.y + p2.y + p3.y) * w2.y
                 + leakyf(p1.z + p2.z + p3.z) * w2.z
                 + leakyf(p1.w + p2.w + p3.w) * w2.w;
      #pragma unroll
      for (int k = 16; k; k >>= 1) part += __shfl_xor(part, k, 64);  // within 32-lane group
      float e = part;

      int key = node * n + tgt;
      unsigned int slot = ((unsigned int)key * 2654435761u) & (unsigned int)(H - 1);
      int fslot = -1;
      while (true) {
        int kk = hkeys[slot];
        if (kk == key) { fslot = (int)slot; break; }
        if (kk == -1) break;
        slot = (slot + 1) & (unsigned int)(H - 1);
      }
      if (fslot >= 0) {  // group-uniform
        float ms = hval[fslot];
        float4 q2 = ldbf4(Q2 + tgt * 128 + 4 * l);
        float gp = leakyf(q1.x + q2.x + b1.x) * g2.x
                 + leakyf(q1.y + q2.y + b1.y) * g2.y
                 + leakyf(q1.z + q2.z + b1.z) * g2.z
                 + leakyf(q1.w + q2.w + b1.w) * g2.w;
        #pragma unroll
        for (int k = 16; k; k >>= 1) gp += __shfl_xor(gp, k, 64);
        float gg = sigmoidf(gp + gb2s);
        e += lg * (gg * ms);   // n_matched > 0 structurally
      }
      if (l == 0) sh_e[j] = e;
    }
    __syncthreads();

    // ---- Phase B: chunk max -> new running max + alpha ----
    float cm = -INFINITY;
    for (int j = tid; j < jmax; j += 256) cm = fmaxf(cm, sh_e[j]);
    #pragma unroll
    for (int k = 32; k; k >>= 1) cm = fmaxf(cm, __shfl_xor(cm, k, 64));
    if ((tid & 63) == 0) r4[tid >> 6] = cm;
    __syncthreads();
    if (tid == 0) {
      float c = fmaxf(fmaxf(r4[0], r4[1]), fmaxf(r4[2], r4[3]));
      float nm = fmaxf(sh_m, c);
      sh_alpha = expf(sh_m - nm);   // first chunk: exp(-inf)=0
      sh_m = nm;
    }
    __syncthreads();
    float m = sh_m, alpha = sh_alpha;

    // ---- Phase C: exp transform + chunk sum ----
    // note: reference clamp min(e-mx,20) is a no-op (e-mx <= 0), so plain exp is exact
    float cs = 0.f;
    for (int j = tid; j < jmax; j += 256) {
      float ex = expf(sh_e[j] - m);
      sh_e[j] = ex;
      cs += ex;
    }
    #pragma unroll
    for (int k = 32; k; k >>= 1) cs += __shfl_xor(cs, k, 64);
    if ((tid & 63) == 0) r4[tid >> 6] = cs;
    __syncthreads();   // sh_e fully transformed + r4 ready
    if (tid == 0) sh_ssum = sh_ssum * alpha + (r4[0] + r4[1] + r4[2] + r4[3]);

    // ---- Phase D: aggregation acc[t] += p_j * Wh[tgt_j][t] (2-way j-parallel) ----
    acc *= alpha;
    int j = jh;
    for (; j + 2 < jmax; j += 4) {
      int t0 = trs[start + base + j].x * 128;
      int t1 = trs[start + base + j + 2].x * 128;
      float e0 = sh_e[j], e1 = sh_e[j + 2];
      float w0 = bf2f(Whb16[t0 + t]), w1 = bf2f(Whb16[t1 + t]);
      acc += e0 * w0 + e1 * w1;
    }
    for (; j < jmax; j += 2) {
      int t0 = trs[start + base + j].x * 128;
      acc += sh_e[j] * bf2f(Whb16[t0 + t]);
    }
  }

  // ---- finalize: combine j-halves, divide, write side & Xb ----
  __syncthreads();
  red[tid] = acc;
  __syncthreads();
  if (tid < 128) {
    float s = (red[tid] + red[tid + 128]) / (sh_ssum + 1e-10f);
    int idx = node * 128 + tid;
    side[idx] = s;
    Xb[idx] = Whb[idx] * s;
  }
}

// ---------- launch ----------
extern "C" void kernel_launch(void* const* d_in, const int* in_sizes, int n_in,
                              void* d_out, int out_size, void* d_ws, size_t ws_size,
                              hipStream_t stream)
{
  const float* h    = (const float*)d_in[0];
  const int* ei     = (const int*)d_in[1];
  const int* etype  = (const int*)d_in[2];
  const float* rel  = (const float*)d_in[3];
  const int* cidx   = (const int*)d_in[4];
  const float* cval = (const float*)d_in[5];
  const int* ctype  = (const int*)d_in[6];
  const float* W    = (const float*)d_in[7];
  const float* Wbi  = (const float*)d_in[8];
  const float* aw1  = (const float*)d_in[9];
  const float* ab1  = (const float*)d_in[10];
  const float* aw2  = (const float*)d_in[11];
  const float* gw1  = (const float*)d_in[12];
  const float* gb1  = (const float*)d_in[13];
  const float* gw2  = (const float*)d_in[14];
  const float* gb2  = (const float*)d_in[15];
  const float* lc   = (const float*)d_in[16];
  const float* lgp  = (const float*)d_in[17];

  const int n = in_sizes[0] / 128;   // 10000
  const int E = in_sizes[2];         // 320000
  const int C = in_sizes[6];         // 50000
  const int R = in_sizes[3] / 128;   // 20
  const int H = HASH_SIZE;

  // scratch layout
  char* ws = (char*)d_ws;
  size_t off = 0;
  auto alloc = [&](size_t bytes) -> void* {
    void* p = ws + off;
    off = (off + bytes + 255) & ~(size_t)255;
    return p;
  };
  float* Whb            = (float*)alloc((size_t)n * 128 * 4);
  unsigned short* Whb16 = (unsigned short*)alloc((size_t)n * 128 * 2);
  unsigned short* P1b   = (unsigned short*)alloc((size_t)n * 128 * 2);
  unsigned short* P2b   = (unsigned short*)alloc((size_t)n * 128 * 2);
  unsigned short* Q1b   = (unsigned short*)alloc((size_t)n * 128 * 2);
  unsigned short* Q2b   = (unsigned short*)alloc((size_t)n * 128 * 2);
  float* Xb    = (float*)alloc((size_t)n * 128 * 4);
  float* P3b   = (float*)alloc((size_t)R * 128 * 4);
  float* side  = (float*)alloc((size_t)n * 128 * 4);
  int2* trs    = (int2*)alloc((size_t)E * 8);
  int* deg     = (int*)alloc((size_t)n * 4);
  int* cursor  = (int*)alloc((size_t)n * 4);
  int* offs    = (int*)alloc((size_t)(n + 1) * 4);
  int* hkeys   = (int*)alloc((size_t)H * 4);
  float* hval  = (float*)alloc((size_t)H * 4);
  (void)ws_size; (void)n_in; (void)out_size;

  dim3 gblk(256);
  dim3 ggrid((n + 63) / 64, 2);

  init_kernel<<<256, 256, 0, stream>>>(deg, cursor, hkeys, hval, n, H);
  hash_build<<<(C + 255) / 256, 256, 0, stream>>>(cidx, cval, ctype, lc, hkeys, hval, C, n, H);
  deg_kernel<<<(E + 255) / 256, 256, 0, stream>>>(ei, deg, E);
  scan_kernel<<<1, 1024, 0, stream>>>(deg, offs, n);
  place_kernel<<<(E + 255) / 256, 256, 0, stream>>>(ei, etype, offs, cursor, trs, E);

  // Wh = h @ W^T (fp32 + bf16 copy)
  gemm_abt<<<ggrid, gblk, 0, stream>>>(h, W, 128, 0, n, Whb, Whb16, 0,
                                       nullptr, nullptr, nullptr);
  p3b_kernel<<<R, 128, 0, stream>>>(rel, aw1, ab1, P3b);
  // P1,P2,Q1,Q2 (bf16) in one dispatch
  gemm4<<<dim3((n + 63) / 64, 8), gblk, 0, stream>>>(Whb, aw1, gw1, P1b, P2b, Q1b, Q2b, n);

  fused_edge_node<<<n, 256, 0, stream>>>(offs, deg, trs, P1b, P2b, P3b, Q1b, Q2b,
                                         aw2, gb1, gw2, gb2, lgp, hkeys, hval,
                                         Whb16, Whb, side, Xb, n, H);

  // bi = X @ W_bi^T ; out = elu(leaky(Wh+side) + leaky(bi) + Wh)
  gemm_abt<<<ggrid, gblk, 0, stream>>>(Xb, Wbi, 128, 0, n, nullptr, nullptr, 1,
                                       Whb, side, (float*)d_out);
}

// Round 6
// 268.896 us; speedup vs baseline: 1.1167x; 1.1167x over previous
//
#include <hip/hip_runtime.h>
#include <stdint.h>

#define SLOPE 0.2f
#define HASH_SIZE 131072  // 2^17, load factor ~0.38 at C=50000

typedef __attribute__((ext_vector_type(8))) short bf16x8;
typedef __attribute__((ext_vector_type(4))) float f32x4;

__device__ __forceinline__ float leakyf(float x) { return x >= 0.f ? x : SLOPE * x; }
__device__ __forceinline__ float sigmoidf(float x) { return 1.f / (1.f + expf(-x)); }
__device__ __forceinline__ unsigned short f2bf(float f) {
  union { float f; unsigned int i; } c; c.f = f;
  unsigned int u = c.i;
  return (unsigned short)((u + 0x7fffu + ((u >> 16) & 1u)) >> 16);  // RNE
}
__device__ __forceinline__ float bf2f(unsigned short u) {
  union { unsigned int i; float f; } c; c.i = ((unsigned int)u) << 16; return c.f;
}
// unpack 4 consecutive bf16 (8B) -> float4
__device__ __forceinline__ float4 ldbf4(const unsigned short* p) {
  uint2 v = *(const uint2*)p;
  union { unsigned int i; float f; } a, b, c, d;
  a.i = v.x << 16; b.i = v.x & 0xffff0000u;
  c.i = v.y << 16; d.i = v.y & 0xffff0000u;
  return make_float4(a.f, b.f, c.f, d.f);
}

// ---------- init: zero deg/cursor, empty hash, pack bf16 weight tables ----------
// Wcat layout: [mat][col][k] bf16, mat: 0=A1 1=A2 2=G1 3=G2 (k-contiguous, 128 each)
__global__ void init_kernel(int* __restrict__ deg, int* __restrict__ cursor,
                            int* __restrict__ hkeys, float* __restrict__ hval,
                            const float* __restrict__ aw1, const float* __restrict__ gw1,
                            unsigned short* __restrict__ Wcat,
                            int n, int H)
{
  int i = blockIdx.x * blockDim.x + threadIdx.x;
  int stride = gridDim.x * blockDim.x;
  for (int j = i; j < n; j += stride) { deg[j] = 0; cursor[j] = 0; }
  for (int j = i; j < H; j += stride) { hkeys[j] = -1; hval[j] = 0.f; }
  for (int j = i; j < 4 * 128 * 128; j += stride) {
    int mat = j >> 14, rest = j & 16383, col = rest >> 7, k = rest & 127;
    float v;
    if (mat == 0)      v = aw1[col * 384 + k];
    else if (mat == 1) v = aw1[col * 384 + 128 + k];
    else if (mat == 2) v = gw1[col * 256 + k];
    else               v = gw1[col * 256 + 128 + k];
    Wcat[j] = f2bf(v);
  }
}

// ---------- fused: degree count (all i<E) + constraint hash build (i<C) ----------
__global__ void hashdeg_kernel(const int* __restrict__ ei, int* __restrict__ deg, int E,
                               const int* __restrict__ cidx, const float* __restrict__ cval,
                               const int* __restrict__ ctype, const float* __restrict__ lc,
                               int* __restrict__ hkeys, float* __restrict__ hval,
                               int C, int n, int H)
{
  int i = blockIdx.x * blockDim.x + threadIdx.x;
  if (i < E) atomicAdd(&deg[ei[i]], 1);
  if (i < C) {
    int key = cidx[i] * n + cidx[C + i];
    float l = sigmoidf(lc[ctype[i]]) * 0.9f + 0.1f;   // lc = sig*(1-0.1)+0.1
    float w = l * cval[i];
    unsigned int slot = ((unsigned int)key * 2654435761u) & (unsigned int)(H - 1);
    while (true) {
      int prev = atomicCAS(&hkeys[slot], -1, key);
      if (prev == -1 || prev == key) break;
      slot = (slot + 1) & (unsigned int)(H - 1);
    }
    atomicAdd(&hval[slot], w);
  }
}

// ---------- per-relation precompute: P3b[r][j] = rel[r]·att_w1[j,256:384] + att_b1[j] ----------
__global__ __launch_bounds__(128) void p3b_kernel(const float* __restrict__ rel,
                                                  const float* __restrict__ aw1,
                                                  const float* __restrict__ ab1,
                                                  float* __restrict__ P3b)
{
  int r = blockIdx.x; int j = threadIdx.x;
  __shared__ float rl[128];
  rl[j] = rel[r * 128 + j];
  __syncthreads();
  float acc = ab1[j];
  const float* wrow = aw1 + j * 384 + 256;
  #pragma unroll 4
  for (int k = 0; k < 128; ++k) acc += rl[k] * wrow[k];
  P3b[r * 128 + j] = acc;
}

// ---------- shared fp32 GEMM body (64x64 tile, 4x4 microtile, K=128) ----------
__device__ __forceinline__ void gemm_body(
    const float* __restrict__ A, const float* __restrict__ B,
    int ldb, int boff, int M, int m0, int n0,
    float (&acc)[4][4], float (*As)[68], float (*Bs)[68])
{
  const int tid = threadIdx.x;
  const int tx = tid & 15, ty = tid >> 4;
  const int lin = tid * 4;
  const int lm = lin >> 4;        // 0..63
  const int lk = lin & 15;        // 0,4,8,12

  for (int kk = 0; kk < 128; kk += 16) {
    __syncthreads();
    {
      int row = m0 + lm;
      if (row < M) {
        float4 v = *(const float4*)(A + row * 128 + kk + lk);
        As[lk + 0][lm] = v.x; As[lk + 1][lm] = v.y;
        As[lk + 2][lm] = v.z; As[lk + 3][lm] = v.w;
      } else {
        As[lk + 0][lm] = 0.f; As[lk + 1][lm] = 0.f;
        As[lk + 2][lm] = 0.f; As[lk + 3][lm] = 0.f;
      }
      int j = n0 + lm;
      float4 w = *(const float4*)(B + j * ldb + boff + kk + lk);
      Bs[lk + 0][lm] = w.x; Bs[lk + 1][lm] = w.y;
      Bs[lk + 2][lm] = w.z; Bs[lk + 3][lm] = w.w;
    }
    __syncthreads();
    #pragma unroll
    for (int k = 0; k < 16; ++k) {
      float a[4], b[4];
      #pragma unroll
      for (int i = 0; i < 4; ++i) a[i] = As[k][ty * 4 + i];
      #pragma unroll
      for (int j = 0; j < 4; ++j) b[j] = Bs[k][tx * 4 + j];
      #pragma unroll
      for (int i = 0; i < 4; ++i)
        #pragma unroll
        for (int j = 0; j < 4; ++j)
          acc[i][j] += a[i] * b[j];
    }
  }
}

// ---------- fp32 GEMM: C = A @ B^T (store fp32 + optional bf16 copy, or fused final epilogue) ----------
__global__ __launch_bounds__(256) void gemm_abt(
    const float* __restrict__ A,
    const float* __restrict__ B, int ldb, int boff, int M,
    float* __restrict__ Cb, unsigned short* __restrict__ C16, int epi,
    const float* __restrict__ Whb,
    const float* __restrict__ side,
    float* __restrict__ outp)
{
  __shared__ float As[16][68];
  __shared__ float Bs[16][68];
  const int m0 = blockIdx.x * 64;
  const int n0 = blockIdx.y * 64;
  float acc[4][4] = {};
  gemm_body(A, B, ldb, boff, M, m0, n0, acc, As, Bs);

  const int tx = (int)threadIdx.x & 15, ty = (int)threadIdx.x >> 4;
  #pragma unroll
  for (int i = 0; i < 4; ++i) {
    int row = m0 + ty * 4 + i;
    if (row >= M) continue;
    int idx0 = row * 128 + n0 + tx * 4;
    if (epi == 0) {
      float4 v4 = make_float4(acc[i][0], acc[i][1], acc[i][2], acc[i][3]);
      *(float4*)(Cb + idx0) = v4;
      if (C16) {
        ushort4 u; u.x = f2bf(v4.x); u.y = f2bf(v4.y); u.z = f2bf(v4.z); u.w = f2bf(v4.w);
        *(ushort4*)(C16 + idx0) = u;
      }
    } else {
      #pragma unroll
      for (int j = 0; j < 4; ++j) {
        int idx = idx0 + j;
        float w = Whb[idx];
        float s = side[idx];
        float hn = leakyf(w + s) + leakyf(acc[i][j]) + w;
        outp[idx] = hn > 0.f ? hn : (expf(hn) - 1.f);
      }
    }
  }
}

// ---------- MFMA GEMM4: {P1,P2,Q1,Q2}[mat] = Whb16 @ Wcat[mat]^T (bf16 in, bf16 out) ----------
// One wave = 16 rows x 128 cols. A-frag: row=lane&15, k=(lane>>4)*8+j.
// B-frag: col=lane&15, k same. C/D: col=lane&15, row=(lane>>4)*4+reg  [m89-verified].
__global__ __launch_bounds__(256) void mfma_gemm4(
    const unsigned short* __restrict__ Whb16,
    const unsigned short* __restrict__ Wcat,
    unsigned short* __restrict__ P1, unsigned short* __restrict__ P2,
    unsigned short* __restrict__ Q1, unsigned short* __restrict__ Q2, int M)
{
  const int wv = (int)threadIdx.x >> 6;
  const int lane = (int)threadIdx.x & 63;
  const int mat = blockIdx.y;
  const int m0 = blockIdx.x * 64 + wv * 16;
  unsigned short* out = (mat == 0) ? P1 : (mat == 1) ? P2 : (mat == 2) ? Q1 : Q2;
  const unsigned short* wb = Wcat + mat * 16384;

  const int r = lane & 15, quad = lane >> 4;
  int arow = m0 + r; if (arow >= M) arow = M - 1;   // clamp; stores are guarded
  const unsigned short* aptr = Whb16 + arow * 128 + quad * 8;
  const unsigned short* bptr = wb + r * 128 + quad * 8;

  f32x4 acc[8] = {};
  #pragma unroll
  for (int ks = 0; ks < 4; ++ks) {
    bf16x8 a = *(const bf16x8*)(aptr + ks * 32);
    #pragma unroll
    for (int ct = 0; ct < 8; ++ct) {
      bf16x8 b = *(const bf16x8*)(bptr + ct * 2048 + ks * 32);
      acc[ct] = __builtin_amdgcn_mfma_f32_16x16x32_bf16(a, b, acc[ct], 0, 0, 0);
    }
  }
  #pragma unroll
  for (int ct = 0; ct < 8; ++ct) {
    #pragma unroll
    for (int rg = 0; rg < 4; ++rg) {
      int row = m0 + quad * 4 + rg;
      if (row < M) out[row * 128 + ct * 16 + r] = f2bf(acc[ct][rg]);
    }
  }
}

// ---------- exclusive scan of deg -> offs (single block, shfl-based) ----------
__global__ __launch_bounds__(1024) void scan_kernel(const int* __restrict__ deg,
                                                    int* __restrict__ offs, int n)
{
  const int ITEMS = (n + 1023) >> 10;    // <=16
  const int t = threadIdx.x;
  const int base = t * ITEMS;
  int local[16];
  int sum = 0;
  for (int i = 0; i < ITEMS; ++i) {
    int idx = base + i;
    int v = (idx < n) ? deg[idx] : 0;
    local[i] = sum;
    sum += v;
  }
  __shared__ int wsum[16];
  int lane = t & 63, w = t >> 6;
  int x = sum;
  #pragma unroll
  for (int d = 1; d < 64; d <<= 1) {
    int y = __shfl_up(x, d, 64);
    if (lane >= d) x += y;
  }
  if (lane == 63) wsum[w] = x;
  __syncthreads();
  if (t == 0) {
    int acc2 = 0;
    for (int i = 0; i < 16; ++i) { int v = wsum[i]; wsum[i] = acc2; acc2 += v; }
  }
  __syncthreads();
  int texcl = wsum[w] + (x - sum);
  for (int i = 0; i < ITEMS; ++i) {
    int idx = base + i;
    if (idx < n) offs[idx] = texcl + local[i];
  }
}

// ---------- bucket edges by src: trs[pos] = (tgt, rtype) in CSR order ----------
__global__ void place_kernel(const int* __restrict__ ei, const int* __restrict__ etype,
                             const int* __restrict__ offs, int* __restrict__ cursor,
                             int2* __restrict__ trs, int E)
{
  int i = blockIdx.x * blockDim.x + threadIdx.x;
  if (i >= E) return;
  int s = ei[i];
  int pos = offs[s] + atomicAdd(&cursor[s], 1);
  trs[pos] = make_int2(ei[E + i], etype[i]);
}

// ---------- fused per-node (one wave/node, two 32-lane groups, register online-softmax) ----------
__global__ __launch_bounds__(256) void fused_node_wave(
  const int* __restrict__ offs, const int* __restrict__ deg,
  const int2* __restrict__ trs,
  const unsigned short* __restrict__ P1, const unsigned short* __restrict__ P2,
  const float* __restrict__ P3b,
  const unsigned short* __restrict__ Q1, const unsigned short* __restrict__ Q2,
  const float* __restrict__ aw2, const float* __restrict__ gb1,
  const float* __restrict__ gw2, const float* __restrict__ gb2,
  const float* __restrict__ lgp,
  const int* __restrict__ hkeys, const float* __restrict__ hval,
  const unsigned short* __restrict__ Whb16, const float* __restrict__ Whb,
  float* __restrict__ side, float* __restrict__ Xb, int n, int H)
{
  const int node = blockIdx.x * 4 + ((int)threadIdx.x >> 6);
  if (node >= n) return;
  const int lane = (int)threadIdx.x & 63;
  const int g = lane >> 5, l = lane & 31;
  const int start = offs[node], cnt = deg[node];

  // node(src)-side preloads: once per wave, not per edge
  float4 p1 = ldbf4(P1 + node * 128 + 4 * l);
  float4 q1 = ldbf4(Q1 + node * 128 + 4 * l);
  float4 w2 = *(const float4*)(aw2 + 4 * l);
  float4 b1 = *(const float4*)(gb1 + 4 * l);
  float4 g2 = *(const float4*)(gw2 + 4 * l);
  float gb2s = gb2[0];
  float lg = sigmoidf(lgp[0]) * 0.9f + 0.1f;

  auto score = [&](int2 tr) -> float {
    int tgt = tr.x, rt = tr.y;
    float4 p2 = ldbf4(P2 + tgt * 128 + 4 * l);
    float4 p3 = *(const float4*)(P3b + rt * 128 + 4 * l);
    float part = leakyf(p1.x + p2.x + p3.x) * w2.x
               + leakyf(p1.y + p2.y + p3.y) * w2.y
               + leakyf(p1.z + p2.z + p3.z) * w2.z
               + leakyf(p1.w + p2.w + p3.w) * w2.w;
    #pragma unroll
    for (int k2 = 16; k2; k2 >>= 1) part += __shfl_xor(part, k2, 64);  // stays in 32-group
    float e = part;
    int key = node * n + tgt;
    unsigned int slot = ((unsigned int)key * 2654435761u) & (unsigned int)(H - 1);
    int fslot = -1;
    while (true) {
      int kk = hkeys[slot];
      if (kk == key) { fslot = (int)slot; break; }
      if (kk == -1) break;
      slot = (slot + 1) & (unsigned int)(H - 1);
    }
    if (fslot >= 0) {   // group-uniform branch
      float ms = hval[fslot];
      float4 q2 = ldbf4(Q2 + tgt * 128 + 4 * l);
      float gp = leakyf(q1.x + q2.x + b1.x) * g2.x
               + leakyf(q1.y + q2.y + b1.y) * g2.y
               + leakyf(q1.z + q2.z + b1.z) * g2.z
               + leakyf(q1.w + q2.w + b1.w) * g2.w;
      #pragma unroll
      for (int k2 = 16; k2; k2 >>= 1) gp += __shfl_xor(gp, k2, 64);
      e += lg * (sigmoidf(gp + gb2s) * ms);   // n_matched > 0 structurally
    }
    return e;
  };

  // group g owns edges j = g, g+2, ...  (ecnt of them)
  const int ecnt = (cnt > g) ? ((cnt - g + 1) >> 1) : 0;
  const int2* tbase = trs + start + g;

  float mg = -INFINITY, sg = 0.f;
  float4 acc = make_float4(0.f, 0.f, 0.f, 0.f);

  int k = 0;
  for (; k + 1 < ecnt; k += 2) {     // unroll x2: two gather chains in flight
    int2 tr0 = tbase[2 * k];
    int2 tr1 = tbase[2 * k + 2];
    float e0 = score(tr0);
    float e1 = score(tr1);
    float4 w0 = ldbf4(Whb16 + tr0.x * 128 + 4 * l);
    float4 w1 = ldbf4(Whb16 + tr1.x * 128 + 4 * l);
    float nm = fmaxf(mg, fmaxf(e0, e1));
    float al = expf(mg - nm);        // first iter: exp(-inf)=0
    float p0 = expf(e0 - nm), p1e = expf(e1 - nm);
    mg = nm;
    sg = sg * al + p0 + p1e;
    acc.x = acc.x * al + p0 * w0.x + p1e * w1.x;
    acc.y = acc.y * al + p0 * w0.y + p1e * w1.y;
    acc.z = acc.z * al + p0 * w0.z + p1e * w1.z;
    acc.w = acc.w * al + p0 * w0.w + p1e * w1.w;
  }
  if (k < ecnt) {
    int2 tr0 = tbase[2 * k];
    float e0 = score(tr0);
    float4 w0 = ldbf4(Whb16 + tr0.x * 128 + 4 * l);
    float nm = fmaxf(mg, e0);
    float al = expf(mg - nm);
    float p0 = expf(e0 - nm);
    mg = nm;
    sg = sg * al + p0;
    acc.x = acc.x * al + p0 * w0.x;
    acc.y = acc.y * al + p0 * w0.y;
    acc.z = acc.z * al + p0 * w0.z;
    acc.w = acc.w * al + p0 * w0.w;
  }

  // merge the two group-halves (lane l of each group holds dims 4l..4l+3)
  float mo = __shfl_xor(mg, 32, 64);
  float nm = fmaxf(mg, mo);
  float al = (mg == -INFINITY) ? 0.f : expf(mg - nm);   // guard -inf - -inf = nan
  float ss = sg * al;
  ss += __shfl_xor(ss, 32, 64);
  acc.x *= al; acc.y *= al; acc.z *= al; acc.w *= al;
  acc.x += __shfl_xor(acc.x, 32, 64);
  acc.y += __shfl_xor(acc.y, 32, 64);
  acc.z += __shfl_xor(acc.z, 32, 64);
  acc.w += __shfl_xor(acc.w, 32, 64);

  float inv = 1.f / (ss + 1e-10f);
  if (g == 0) {
    int idx = node * 128 + 4 * l;
    float4 s = make_float4(acc.x * inv, acc.y * inv, acc.z * inv, acc.w * inv);
    *(float4*)(side + idx) = s;
    float4 wh = *(const float4*)(Whb + idx);
    *(float4*)(Xb + idx) = make_float4(wh.x * s.x, wh.y * s.y, wh.z * s.z, wh.w * s.w);
  }
}

// ---------- launch ----------
extern "C" void kernel_launch(void* const* d_in, const int* in_sizes, int n_in,
                              void* d_out, int out_size, void* d_ws, size_t ws_size,
                              hipStream_t stream)
{
  const float* h    = (const float*)d_in[0];
  const int* ei     = (const int*)d_in[1];
  const int* etype  = (const int*)d_in[2];
  const float* rel  = (const float*)d_in[3];
  const int* cidx   = (const int*)d_in[4];
  const float* cval = (const float*)d_in[5];
  const int* ctype  = (const int*)d_in[6];
  const float* W    = (const float*)d_in[7];
  const float* Wbi  = (const float*)d_in[8];
  const float* aw1  = (const float*)d_in[9];
  const float* ab1  = (const float*)d_in[10];
  const float* aw2  = (const float*)d_in[11];
  const float* gw1  = (const float*)d_in[12];
  const float* gb1  = (const float*)d_in[13];
  const float* gw2  = (const float*)d_in[14];
  const float* gb2  = (const float*)d_in[15];
  const float* lc   = (const float*)d_in[16];
  const float* lgp  = (const float*)d_in[17];

  const int n = in_sizes[0] / 128;   // 10000
  const int E = in_sizes[2];         // 320000
  const int C = in_sizes[6];         // 50000
  const int R = in_sizes[3] / 128;   // 20
  const int H = HASH_SIZE;

  // scratch layout
  char* ws = (char*)d_ws;
  size_t off = 0;
  auto alloc = [&](size_t bytes) -> void* {
    void* p = ws + off;
    off = (off + bytes + 255) & ~(size_t)255;
    return p;
  };
  float* Whb            = (float*)alloc((size_t)n * 128 * 4);
  unsigned short* Whb16 = (unsigned short*)alloc((size_t)n * 128 * 2);
  unsigned short* P1b   = (unsigned short*)alloc((size_t)n * 128 * 2);
  unsigned short* P2b   = (unsigned short*)alloc((size_t)n * 128 * 2);
  unsigned short* Q1b   = (unsigned short*)alloc((size_t)n * 128 * 2);
  unsigned short* Q2b   = (unsigned short*)alloc((size_t)n * 128 * 2);
  unsigned short* Wcat  = (unsigned short*)alloc((size_t)4 * 128 * 128 * 2);
  float* Xb    = (float*)alloc((size_t)n * 128 * 4);
  float* P3b   = (float*)alloc((size_t)R * 128 * 4);
  float* side  = (float*)alloc((size_t)n * 128 * 4);
  int2* trs    = (int2*)alloc((size_t)E * 8);
  int* deg     = (int*)alloc((size_t)n * 4);
  int* cursor  = (int*)alloc((size_t)n * 4);
  int* offs    = (int*)alloc((size_t)(n + 1) * 4);
  int* hkeys   = (int*)alloc((size_t)H * 4);
  float* hval  = (float*)alloc((size_t)H * 4);
  (void)ws_size; (void)n_in; (void)out_size;

  dim3 gblk(256);
  dim3 ggrid((n + 63) / 64, 2);

  init_kernel<<<256, 256, 0, stream>>>(deg, cursor, hkeys, hval, aw1, gw1, Wcat, n, H);
  hashdeg_kernel<<<(E + 255) / 256, 256, 0, stream>>>(ei, deg, E, cidx, cval, ctype, lc,
                                                      hkeys, hval, C, n, H);
  scan_kernel<<<1, 1024, 0, stream>>>(deg, offs, n);
  place_kernel<<<(E + 255) / 256, 256, 0, stream>>>(ei, etype, offs, cursor, trs, E);

  // Wh = h @ W^T (fp32 + bf16 copy)
  gemm_abt<<<ggrid, gblk, 0, stream>>>(h, W, 128, 0, n, Whb, Whb16, 0,
                                       nullptr, nullptr, nullptr);
  p3b_kernel<<<R, 128, 0, stream>>>(rel, aw1, ab1, P3b);
  // P1,P2,Q1,Q2 via bf16 MFMA
  mfma_gemm4<<<dim3((n + 63) / 64, 4), gblk, 0, stream>>>(Whb16, Wcat,
                                                          P1b, P2b, Q1b, Q2b, n);

  fused_node_wave<<<(n + 3) / 4, 256, 0, stream>>>(offs, deg, trs, P1b, P2b, P3b,
                                                   Q1b, Q2b, aw2, gb1, gw2, gb2, lgp,
                                                   hkeys, hval, Whb16, Whb, side, Xb, n, H);

  // bi = X @ W_bi^T ; out = elu(leaky(Wh+side) + leaky(bi) + Wh)
  gemm_abt<<<ggrid, gblk, 0, stream>>>(Xb, Wbi, 128, 0, n, nullptr, nullptr, 1,
                                       Whb, side, (float*)d_out);
}